// Round 10
// baseline (187.058 us; speedup 1.0000x reference)
//
#include <hip/hip_runtime.h>
#include <math.h>

// EquiTritonModel: N=10000 nodes, E=160000 edges, D=32, H=16, NB=16.
// R9 -> R10: gather stuck at ~45us across 3 load structures (R5/R7/R9) =>
// the wall is the serial per-node loop (4 iters x 135-instr body, latency
// exposed, only 10k waves). Split it:
//  - m_kernel: EDGE-parallel (1 group=1 edge, no loop): h0 recurrence +
//    T-contraction (TI float2-interleaved: 16 dwordx2/edge), writes finished
//    per-edge contribution float4 (K0*m0, K1*m1*u) to mbuf (41MB, in ws).
//  - node_kernel: per-node wave sums ~16 float4s (15-instr loop body) +
//    G-epilogue + readout (same math/order as R9's gather epilogue).

namespace {
constexpr int   NATOMS   = 100;
constexpr int   CAP      = 64;
constexpr float PI_F     = 3.14159265358979323846f;
constexpr float INV4PI_F = 0.28209479177387814f;   // 1/sqrt(4*pi)
constexpr float SQRT3_F  = 1.7320508075688772f;
constexpr float CUT_F    = 6.0f;
constexpr float BASIS_C  = 2.3094010767585034f;    // sqrt(2/6)*sqrt(16)
constexpr float N0_F     = 0.17677669529663687f;   // 1/sqrt(32)
constexpr float K0_F = INV4PI_F * N0_F * 0.0625f;
constexpr float K1_F = SQRT3_F * INV4PI_F * N0_F * 0.0625f;
}

__device__ __forceinline__ float silu_fast(float x) {
  return x / (1.0f + __expf(-x));
}

__device__ __forceinline__ float block_reduce_sum(float v) {
  #pragma unroll
  for (int o = 32; o > 0; o >>= 1) v += __shfl_down(v, o, 64);
  __shared__ float ls[8];
  int lane = threadIdx.x & 63;
  int w    = threadIdx.x >> 6;
  if (lane == 0) ls[w] = v;
  __syncthreads();
  float s = 0.f;
  if (threadIdx.x == 0) {
    int nw = (blockDim.x + 63) >> 6;
    for (int i = 0; i < nw; ++i) s += ls[i];
  }
  return s;
}

// ---------------------------------------------------------------------------
// Setup.
//  blocks [0,NATOMS): TI[a][j][2h+{0,1}] float2-interleaved T tables.
//  block NATOMS:      G1T/G4T [comp][hidden] (transposed).
//  blocks >NATOMS:    evec[e]=(ux,uy,uz,dist); ea[e]=an[src];
//                     elist[d*CAP+pos]=e (edge INDEX).
// ---------------------------------------------------------------------------
__global__ void setup_kernel(const float* __restrict__ atom_emb,
                             const float* __restrict__ fc0_w2,
                             const float* __restrict__ fc1_w2,
                             const float* __restrict__ w_readout,
                             const int* __restrict__ ei,
                             const float* __restrict__ coords,
                             const int* __restrict__ an,
                             float* __restrict__ TI,
                             float* __restrict__ G1T, float* __restrict__ G4T,
                             int* __restrict__ cursor,
                             float4* __restrict__ evec,
                             int* __restrict__ ea,
                             int* __restrict__ elist,
                             int E) {
  int b = blockIdx.x;
  int tt = threadIdx.x;
  if (b < NATOMS) {
    int j = tt >> 4;    // hidden (h0) index
    int h = tt & 15;    // H-component
    float s0 = 0.f, s1 = 0.f;
    #pragma unroll
    for (int d = 0; d < 32; ++d) {
      float x = atom_emb[b * 32 + d];
      s0 = fmaf(x, fc0_w2[j * 1024 + d * 16 + h], s0);
      s1 = fmaf(x, fc0_w2[j * 1024 + 512 + d * 16 + h], s1);
    }
    TI[b * 512 + j * 32 + 2 * h]     = s0;  // lane h: float2 at (j*16+h)
    TI[b * 512 + j * 32 + 2 * h + 1] = s1;
  } else if (b == NATOMS) {
    int j = tt >> 4;
    int h = tt & 15;
    float g1 = 0.f, g4 = 0.f;
    #pragma unroll
    for (int k = 0; k < 16; ++k) {
      float r = w_readout[k];
      g1 = fmaf(fc1_w2[j * 1024 + h * 16 + k], r, g1);
      g4 = fmaf(fc1_w2[j * 1024 + 768 + h * 16 + k], r, g4);
    }
    G1T[h * 16 + j] = g1;    // [comp][hidden]: column t lane-consecutive
    G4T[h * 16 + j] = g4;
  } else {
    int e = (b - NATOMS - 1) * blockDim.x + tt;
    if (e < E) {
      int s = ei[e];
      int d = ei[E + e];
      float vx = coords[3 * s + 0] - coords[3 * d + 0];
      float vy = coords[3 * s + 1] - coords[3 * d + 1];
      float vz = coords[3 * s + 2] - coords[3 * d + 2];
      float dist = sqrtf(vx * vx + vy * vy + vz * vz);
      float inv  = 1.0f / fmaxf(dist, 1e-9f);
      evec[e] = make_float4(vx * inv, vy * inv, vz * inv, dist);
      ea[e] = an[s];
      int pos = atomicAdd(&cursor[d], 1);
      if (pos < CAP) elist[d * CAP + pos] = e;
    }
  }
}

// ---------------------------------------------------------------------------
// m_kernel: edge-parallel. 256 thr = 16 groups of 16 lanes; group handles
// edges b*32+g and b*32+16+g (no serial node loop). Lane t owns component t.
// Writes mbuf[e*16+t] = (K0*m0_t, K1*m1_t*ux, K1*m1_t*uy, K1*m1_t*uz).
// ---------------------------------------------------------------------------
__global__ void __launch_bounds__(256)
m_kernel(const float4* __restrict__ evec,
         const int* __restrict__ ea,
         const float* __restrict__ TI,
         const float* __restrict__ fc0_w1,
         float4* __restrict__ mbuf,
         int E) {
  __shared__ float w1s[256];
  w1s[threadIdx.x] = fc0_w1[threadIdx.x];
  __syncthreads();
  int lane = threadIdx.x & 63;
  int g    = threadIdx.x >> 4;       // block group 0..15
  int t    = threadIdx.x & 15;
  int base = lane & 48;

  float w0c[16];
  #pragma unroll
  for (int k = 0; k < 16; ++k) w0c[k] = w1s[k * 16 + t];

  const float angc = PI_F / CUT_F;
  int e = blockIdx.x * 32 + g;
  #pragma unroll
  for (int rep = 0; rep < 2; ++rep, e += 16) {
    if (e < E) {
      float4 ev = evec[e];            // group-uniform broadcast
      int    a  = ea[e];
      float dist = ev.w;
      float bc = (dist < CUT_F) ? (BASIS_C / fmaxf(dist, 1e-9f)) : 0.0f;

      float ang = angc * dist;
      float sc = __sinf(ang);
      float tw = 2.0f * __cosf(ang);
      float sp = 0.f, acc = 0.f;
      #pragma unroll
      for (int k = 0; k < 16; ++k) {
        acc = fmaf(sc, w0c[k], acc);
        float sn = fmaf(tw, sc, -sp);
        sp = sc; sc = sn;
      }
      float h0t = silu_fast(acc * bc * 0.25f);

      const float2* tp = (const float2*)(TI + a * 512) + t;
      float u0 = 0.f, u1 = 0.f;
      #pragma unroll
      for (int j = 0; j < 16; ++j) {
        float hj = __shfl(h0t, base + j, 64);
        float2 T = tp[j * 16];
        u0 = fmaf(hj, T.x, u0);
        u1 = fmaf(hj, T.y, u1);
      }
      float m1 = K1_F * u1;
      mbuf[(size_t)e * 16 + t] =
          make_float4(K0_F * u0, m1 * ev.x, m1 * ev.y, m1 * ev.z);
    }
  }
}

// ---------------------------------------------------------------------------
// node_kernel: 256 thr = 4 waves = 4 nodes/block; 4 groups x 16 lanes.
// Sums the node's per-edge float4 contributions (i = g::4, same order as
// R9), butterfly, G-epilogue -> zbuf[node*64 + t*4 + g], readout into out.
// ---------------------------------------------------------------------------
__global__ void __launch_bounds__(256, 4)
node_kernel(const int* __restrict__ elist,
            const int* __restrict__ cursor,
            const float4* __restrict__ mbuf,
            const float* __restrict__ G1T,
            const float* __restrict__ G4T,
            const float* __restrict__ w_readout,
            float* __restrict__ zbuf,
            float* __restrict__ out,
            int N) {
  __shared__ float ggs[512];          // [0:256)=G1T, [256:512)=G4T
  ggs[threadIdx.x]       = G1T[threadIdx.x];
  ggs[256 + threadIdx.x] = G4T[threadIdx.x];
  __syncthreads();

  int wave = threadIdx.x >> 6;
  int lane = threadIdx.x & 63;
  int g    = lane >> 4;
  int t    = lane & 15;
  int base = lane & 48;
  int node = blockIdx.x * 4 + wave;
  bool valid = node < N;

  float rr = w_readout[t];
  int cnt = valid ? min(cursor[node], CAP) : 0;
  const int* eb = elist + (size_t)(valid ? node : 0) * CAP;

  float a0 = 0.f, ax = 0.f, ay = 0.f, az = 0.f;
  for (int i = g; i < cnt; i += 4) {
    int eidx = eb[i];
    float4 f = mbuf[(size_t)eidx * 16 + t];
    a0 += f.x; ax += f.y; ay += f.z; az += f.w;
  }

  a0 += __shfl_xor(a0, 16, 64); a0 += __shfl_xor(a0, 32, 64);
  ax += __shfl_xor(ax, 16, 64); ax += __shfl_xor(ax, 32, 64);
  ay += __shfl_xor(ay, 16, 64); ay += __shfl_xor(ay, 32, 64);
  az += __shfl_xor(az, 16, 64); az += __shfl_xor(az, 32, 64);

  // epilogue: group 0 -> Q (G1), groups 1..3 -> P (G4); K already applied
  float srcv = (g == 0) ? a0 : ((g == 1) ? ax : (g == 2) ? ay : az);
  int tofs = (g == 0) ? 0 : 256;
  float o = 0.f;
  #pragma unroll
  for (int h = 0; h < 16; ++h) {
    float vh = __shfl(srcv, base + h, 64);
    o = fmaf(ggs[tofs + h * 16 + t], vh, o);
  }
  if (valid) zbuf[(size_t)node * 64 + t * 4 + g] = o;

  // node readout partial: 0.25 * sum_t z0_t * r_t (group 0 holds z0=a0)
  float p = (valid && g == 0) ? a0 * rr : 0.f;
  float tot = block_reduce_sum(p);
  if (threadIdx.x == 0) atomicAdd(out, tot * 0.25f);
}

// ---------------------------------------------------------------------------
// Phase 2: one 16-lane group per edge (grid-stride). Lane t owns j=t.
// c_e = (INV4PI*N0/64) * sum_j h1_j * (Q_j + P_j . u)
// ---------------------------------------------------------------------------
__global__ void __launch_bounds__(256, 4)
phase2_kernel(const int* __restrict__ ei,
              const float4* __restrict__ evec,
              const float* __restrict__ fc1_w1,
              const float* __restrict__ zbuf,
              float* __restrict__ out,
              int E) {
  int t = threadIdx.x & 15;
  float w1c[16];
  #pragma unroll
  for (int k = 0; k < 16; ++k) w1c[k] = fc1_w1[k * 16 + t];

  int gid = (blockIdx.x * blockDim.x + threadIdx.x) >> 4;
  int ngroups = (gridDim.x * blockDim.x) >> 4;
  const float angc = PI_F / CUT_F;

  float c = 0.f;
  for (int e = gid; e < E; e += ngroups) {
    int s = ei[e];
    float4 ev = evec[e];
    float dist = ev.w;
    float bc = (dist < CUT_F) ? (BASIS_C / fmaxf(dist, 1e-9f)) : 0.0f;

    float ang = angc * dist;
    float sc = __sinf(ang);
    float tw = 2.0f * __cosf(ang);
    float sp = 0.f, acc = 0.f;
    #pragma unroll
    for (int k = 0; k < 16; ++k) {
      acc = fmaf(sc, w1c[k], acc);
      float sn = fmaf(tw, sc, -sp);
      sp = sc; sc = sn;
    }
    float h1t = silu_fast(acc * bc * 0.25f);

    float4 z = ((const float4*)(zbuf + (size_t)s * 64))[t];
    c = fmaf(h1t, fmaf(z.y, ev.x, fmaf(z.z, ev.y, fmaf(z.w, ev.z, z.x))), c);
  }
  c *= INV4PI_F * N0_F * (1.0f / 64.0f);
  float tot = block_reduce_sum(c);
  if (threadIdx.x == 0) atomicAdd(out, tot);
}

extern "C" void kernel_launch(void* const* d_in, const int* in_sizes, int n_in,
                              void* d_out, int out_size, void* d_ws, size_t ws_size,
                              hipStream_t stream) {
  const int*   an        = (const int*)d_in[0];
  const float* coords    = (const float*)d_in[1];
  const int*   ei        = (const int*)d_in[2];
  const float* atom_emb  = (const float*)d_in[3];
  const float* fc0_w1    = (const float*)d_in[4];
  const float* fc0_w2    = (const float*)d_in[5];
  const float* fc1_w1    = (const float*)d_in[6];
  const float* fc1_w2    = (const float*)d_in[7];
  const float* w_readout = (const float*)d_in[8];

  int N = in_sizes[0];
  int E = in_sizes[2] / 2;

  // ws layout (float4 arrays first for 16B alignment); ws is ~256MB.
  float4* evec = (float4*)d_ws;                    // E
  float4* mbuf = evec + E;                         // E*16  (~41 MB)
  float*  zbuf = (float*)(mbuf + (size_t)E * 16);  // N*64
  float*  TI   = zbuf + (size_t)N * 64;            // 100*512
  float*  G1T  = TI + NATOMS * 512;                // 256
  float*  G4T  = G1T + 256;                        // 256
  int*    cursor = (int*)(G4T + 256);              // N
  int*    ea     = cursor + N;                     // E
  int*    elist  = ea + E;                         // N*CAP
  float*  out = (float*)d_out;

  hipMemsetAsync(cursor, 0, (size_t)N * sizeof(int), stream);
  hipMemsetAsync(out, 0, sizeof(float), stream);

  int blk = 256;
  int ebkts = (E + blk - 1) / blk;
  setup_kernel<<<NATOMS + 1 + ebkts, blk, 0, stream>>>(
      atom_emb, fc0_w2, fc1_w2, w_readout, ei, coords, an,
      TI, G1T, G4T, cursor, evec, ea, elist, E);

  m_kernel<<<(E + 31) / 32, blk, 0, stream>>>(evec, ea, TI, fc0_w1, mbuf, E);

  node_kernel<<<(N + 3) / 4, blk, 0, stream>>>(
      elist, cursor, mbuf, G1T, G4T, w_readout, zbuf, out, N);

  phase2_kernel<<<2048, blk, 0, stream>>>(ei, evec, fc1_w1, zbuf, out, E);
}

// Round 11
// 176.955 us; speedup vs baseline: 1.0571x; 1.0571x over previous
//
#include <hip/hip_runtime.h>
#include <math.h>

// EquiTritonModel: N=10000 nodes, E=160000 edges, D=32, H=16, NB=16.
// R10 -> R11: node_kernel's 42us was random 64B gathers from edge-ordered
// mbuf (VALUBusy 5%). Fix: producer-scatter / consumer-stream. The edge
// kernel allocates its bucket slot (atomicAdd on cursor[dst], lane 0,
// shfl-broadcast) and writes its finished 256B contribution directly to
// mbuf[dst*CAP+pos]; node_kernel reads node-contiguous slots (streaming,
// ~1KB/wave). elist/eslot and the bucket pass are gone: 4 kernels.

namespace {
constexpr int   NATOMS   = 100;
constexpr int   CAP      = 64;   // Poisson(16): P(deg>=64) ~ 1e-19
constexpr float PI_F     = 3.14159265358979323846f;
constexpr float INV4PI_F = 0.28209479177387814f;   // 1/sqrt(4*pi)
constexpr float SQRT3_F  = 1.7320508075688772f;
constexpr float CUT_F    = 6.0f;
constexpr float BASIS_C  = 2.3094010767585034f;    // sqrt(2/6)*sqrt(16)
constexpr float N0_F     = 0.17677669529663687f;   // 1/sqrt(32)
constexpr float K0_F = INV4PI_F * N0_F * 0.0625f;
constexpr float K1_F = SQRT3_F * INV4PI_F * N0_F * 0.0625f;
}

__device__ __forceinline__ float silu_fast(float x) {
  return x / (1.0f + __expf(-x));
}

__device__ __forceinline__ float block_reduce_sum(float v) {
  #pragma unroll
  for (int o = 32; o > 0; o >>= 1) v += __shfl_down(v, o, 64);
  __shared__ float ls[8];
  int lane = threadIdx.x & 63;
  int w    = threadIdx.x >> 6;
  if (lane == 0) ls[w] = v;
  __syncthreads();
  float s = 0.f;
  if (threadIdx.x == 0) {
    int nw = (blockDim.x + 63) >> 6;
    for (int i = 0; i < nw; ++i) s += ls[i];
  }
  return s;
}

// ---------------------------------------------------------------------------
// Tables: blocks [0,NATOMS) -> TI[a][j][2h+{0,1}] (float2-interleaved);
// block NATOMS -> G1T/G4T [comp][hidden] (transposed).
// ---------------------------------------------------------------------------
__global__ void table_kernel(const float* __restrict__ atom_emb,
                             const float* __restrict__ fc0_w2,
                             const float* __restrict__ fc1_w2,
                             const float* __restrict__ w_readout,
                             float* __restrict__ TI,
                             float* __restrict__ G1T, float* __restrict__ G4T) {
  int b = blockIdx.x;
  int tt = threadIdx.x;
  int j = tt >> 4;
  int h = tt & 15;
  if (b < NATOMS) {
    float s0 = 0.f, s1 = 0.f;
    #pragma unroll
    for (int d = 0; d < 32; ++d) {
      float x = atom_emb[b * 32 + d];
      s0 = fmaf(x, fc0_w2[j * 1024 + d * 16 + h], s0);
      s1 = fmaf(x, fc0_w2[j * 1024 + 512 + d * 16 + h], s1);
    }
    TI[b * 512 + j * 32 + 2 * h]     = s0;  // lane h: float2 at (j*16+h)
    TI[b * 512 + j * 32 + 2 * h + 1] = s1;
  } else {
    float g1 = 0.f, g4 = 0.f;
    #pragma unroll
    for (int k = 0; k < 16; ++k) {
      float r = w_readout[k];
      g1 = fmaf(fc1_w2[j * 1024 + h * 16 + k], r, g1);
      g4 = fmaf(fc1_w2[j * 1024 + 768 + h * 16 + k], r, g4);
    }
    G1T[h * 16 + j] = g1;    // [comp][hidden]: column t lane-consecutive
    G4T[h * 16 + j] = g4;
  }
}

// ---------------------------------------------------------------------------
// edge_kernel: one 16-lane group per edge, 2 edges/group. Computes
// evec[e]=(ux,uy,uz,dist) (for phase2), h0 via sine recurrence, T
// contraction; lane 0 allocates bucket slot pos=atomicAdd(cursor[dst]);
// writes mbuf[(dst*CAP+pos)*16 + t] = (K0*m0, K1*m1*u) (256B chunk).
// ---------------------------------------------------------------------------
__global__ void __launch_bounds__(256)
edge_kernel(const int* __restrict__ ei,
            const float* __restrict__ coords,
            const int* __restrict__ an,
            const float* __restrict__ TI,
            const float* __restrict__ fc0_w1,
            int* __restrict__ cursor,
            float4* __restrict__ evec,
            float4* __restrict__ mbuf,
            int E) {
  __shared__ float w1s[256];
  w1s[threadIdx.x] = fc0_w1[threadIdx.x];
  __syncthreads();
  int lane = threadIdx.x & 63;
  int g    = threadIdx.x >> 4;       // block group 0..15
  int t    = threadIdx.x & 15;
  int base = lane & 48;

  float w0c[16];
  #pragma unroll
  for (int k = 0; k < 16; ++k) w0c[k] = w1s[k * 16 + t];

  const float angc = PI_F / CUT_F;
  int e = blockIdx.x * 32 + g;
  #pragma unroll
  for (int rep = 0; rep < 2; ++rep, e += 16) {
    if (e < E) {
      int s = ei[e];
      int d = ei[E + e];
      float vx = coords[3 * s + 0] - coords[3 * d + 0];
      float vy = coords[3 * s + 1] - coords[3 * d + 1];
      float vz = coords[3 * s + 2] - coords[3 * d + 2];
      float dist = sqrtf(vx * vx + vy * vy + vz * vz);
      float inv  = 1.0f / fmaxf(dist, 1e-9f);
      float ux = vx * inv, uy = vy * inv, uz = vz * inv;
      float bc = (dist < CUT_F) ? (BASIS_C * inv) : 0.0f;

      int slotv = 0;
      if (t == 0) {
        evec[e] = make_float4(ux, uy, uz, dist);
        slotv = d * CAP + atomicAdd(&cursor[d], 1);
      }
      int slot = __shfl(slotv, base, 64);

      // h0_t via sine recurrence
      float ang = angc * dist;
      float sc = __sinf(ang);
      float tw = 2.0f * __cosf(ang);
      float sp = 0.f, acc = 0.f;
      #pragma unroll
      for (int k = 0; k < 16; ++k) {
        acc = fmaf(sc, w0c[k], acc);
        float sn = fmaf(tw, sc, -sp);
        sp = sc; sc = sn;
      }
      float h0t = silu_fast(acc * bc * 0.25f);

      int a = an[s];
      const float2* tp = (const float2*)(TI + a * 512) + t;
      float u0 = 0.f, u1 = 0.f;
      #pragma unroll
      for (int j = 0; j < 16; ++j) {
        float hj = __shfl(h0t, base + j, 64);
        float2 T = tp[j * 16];
        u0 = fmaf(hj, T.x, u0);
        u1 = fmaf(hj, T.y, u1);
      }
      float m1 = K1_F * u1;
      mbuf[(size_t)slot * 16 + t] =
          make_float4(K0_F * u0, m1 * ux, m1 * uy, m1 * uz);
    }
  }
}

// ---------------------------------------------------------------------------
// node_kernel: 256 thr = 4 waves = 4 nodes/block; 4 groups x 16 lanes.
// Streams the node's bucketed contributions (contiguous slots), butterfly,
// G-epilogue -> zbuf[node*64 + t*4 + g], readout into out.
// ---------------------------------------------------------------------------
__global__ void __launch_bounds__(256, 4)
node_kernel(const int* __restrict__ cursor,
            const float4* __restrict__ mbuf,
            const float* __restrict__ G1T,
            const float* __restrict__ G4T,
            const float* __restrict__ w_readout,
            float* __restrict__ zbuf,
            float* __restrict__ out,
            int N) {
  __shared__ float ggs[512];          // [0:256)=G1T, [256:512)=G4T
  ggs[threadIdx.x]       = G1T[threadIdx.x];
  ggs[256 + threadIdx.x] = G4T[threadIdx.x];
  __syncthreads();

  int wave = threadIdx.x >> 6;
  int lane = threadIdx.x & 63;
  int g    = lane >> 4;
  int t    = lane & 15;
  int base = lane & 48;
  int node = blockIdx.x * 4 + wave;
  bool valid = node < N;

  float rr = w_readout[t];
  int cnt = valid ? min(cursor[node], CAP) : 0;
  const float4* mb = mbuf + (size_t)(valid ? node : 0) * CAP * 16;

  float a0 = 0.f, ax = 0.f, ay = 0.f, az = 0.f;
  for (int i = g; i < cnt; i += 4) {
    float4 f = mb[i * 16 + t];        // wave reads 4 consecutive 256B slots
    a0 += f.x; ax += f.y; ay += f.z; az += f.w;
  }

  a0 += __shfl_xor(a0, 16, 64); a0 += __shfl_xor(a0, 32, 64);
  ax += __shfl_xor(ax, 16, 64); ax += __shfl_xor(ax, 32, 64);
  ay += __shfl_xor(ay, 16, 64); ay += __shfl_xor(ay, 32, 64);
  az += __shfl_xor(az, 16, 64); az += __shfl_xor(az, 32, 64);

  // epilogue: group 0 -> Q (G1), groups 1..3 -> P (G4); K already applied
  float srcv = (g == 0) ? a0 : ((g == 1) ? ax : (g == 2) ? ay : az);
  int tofs = (g == 0) ? 0 : 256;
  float o = 0.f;
  #pragma unroll
  for (int h = 0; h < 16; ++h) {
    float vh = __shfl(srcv, base + h, 64);
    o = fmaf(ggs[tofs + h * 16 + t], vh, o);
  }
  if (valid) zbuf[(size_t)node * 64 + t * 4 + g] = o;

  // node readout partial: 0.25 * sum_t z0_t * r_t (group 0 holds z0=a0)
  float p = (valid && g == 0) ? a0 * rr : 0.f;
  float tot = block_reduce_sum(p);
  if (threadIdx.x == 0) atomicAdd(out, tot * 0.25f);
}

// ---------------------------------------------------------------------------
// Phase 2: one 16-lane group per edge (grid-stride). Lane t owns j=t.
// c_e = (INV4PI*N0/64) * sum_j h1_j * (Q_j + P_j . u)
// ---------------------------------------------------------------------------
__global__ void __launch_bounds__(256, 4)
phase2_kernel(const int* __restrict__ ei,
              const float4* __restrict__ evec,
              const float* __restrict__ fc1_w1,
              const float* __restrict__ zbuf,
              float* __restrict__ out,
              int E) {
  int t = threadIdx.x & 15;
  float w1c[16];
  #pragma unroll
  for (int k = 0; k < 16; ++k) w1c[k] = fc1_w1[k * 16 + t];

  int gid = (blockIdx.x * blockDim.x + threadIdx.x) >> 4;
  int ngroups = (gridDim.x * blockDim.x) >> 4;
  const float angc = PI_F / CUT_F;

  float c = 0.f;
  for (int e = gid; e < E; e += ngroups) {
    int s = ei[e];
    float4 ev = evec[e];
    float dist = ev.w;
    float bc = (dist < CUT_F) ? (BASIS_C / fmaxf(dist, 1e-9f)) : 0.0f;

    float ang = angc * dist;
    float sc = __sinf(ang);
    float tw = 2.0f * __cosf(ang);
    float sp = 0.f, acc = 0.f;
    #pragma unroll
    for (int k = 0; k < 16; ++k) {
      acc = fmaf(sc, w1c[k], acc);
      float sn = fmaf(tw, sc, -sp);
      sp = sc; sc = sn;
    }
    float h1t = silu_fast(acc * bc * 0.25f);

    float4 z = ((const float4*)(zbuf + (size_t)s * 64))[t];
    c = fmaf(h1t, fmaf(z.y, ev.x, fmaf(z.z, ev.y, fmaf(z.w, ev.z, z.x))), c);
  }
  c *= INV4PI_F * N0_F * (1.0f / 64.0f);
  float tot = block_reduce_sum(c);
  if (threadIdx.x == 0) atomicAdd(out, tot);
}

extern "C" void kernel_launch(void* const* d_in, const int* in_sizes, int n_in,
                              void* d_out, int out_size, void* d_ws, size_t ws_size,
                              hipStream_t stream) {
  const int*   an        = (const int*)d_in[0];
  const float* coords    = (const float*)d_in[1];
  const int*   ei        = (const int*)d_in[2];
  const float* atom_emb  = (const float*)d_in[3];
  const float* fc0_w1    = (const float*)d_in[4];
  const float* fc0_w2    = (const float*)d_in[5];
  const float* fc1_w1    = (const float*)d_in[6];
  const float* fc1_w2    = (const float*)d_in[7];
  const float* w_readout = (const float*)d_in[8];

  int N = in_sizes[0];
  int E = in_sizes[2] / 2;

  // ws layout: mbuf first (bucketed, N*CAP slots x 256B = ~164MB), then rest.
  float4* mbuf = (float4*)d_ws;                        // N*CAP*16
  float4* evec = mbuf + (size_t)N * CAP * 16;          // E
  float*  zbuf = (float*)(evec + E);                   // N*64
  float*  TI   = zbuf + (size_t)N * 64;                // 100*512
  float*  G1T  = TI + NATOMS * 512;                    // 256
  float*  G4T  = G1T + 256;                            // 256
  int*    cursor = (int*)(G4T + 256);                  // N
  float*  out = (float*)d_out;

  hipMemsetAsync(cursor, 0, (size_t)N * sizeof(int), stream);
  hipMemsetAsync(out, 0, sizeof(float), stream);

  int blk = 256;
  table_kernel<<<NATOMS + 1, blk, 0, stream>>>(
      atom_emb, fc0_w2, fc1_w2, w_readout, TI, G1T, G4T);

  edge_kernel<<<(E + 31) / 32, blk, 0, stream>>>(
      ei, coords, an, TI, fc0_w1, cursor, evec, mbuf, E);

  node_kernel<<<(N + 3) / 4, blk, 0, stream>>>(
      cursor, mbuf, G1T, G4T, w_readout, zbuf, out, N);

  phase2_kernel<<<2048, blk, 0, stream>>>(ei, evec, fc1_w1, zbuf, out, E);
}

// Round 12
// 151.279 us; speedup vs baseline: 1.2365x; 1.1697x over previous
//
#include <hip/hip_runtime.h>
#include <math.h>

// EquiTritonModel: N=10000 nodes, E=160000 edges, D=32, H=16, NB=16.
// R11 -> R12:
//  - phase2 FUSED into node_kernel: after butterfly+G-transform the wave
//    holds Q/Px/Py/Pz in registers (4 shfls to distribute); edge_kernel
//    buckets (ux,uy,uz,dist) by SRC (sbuf) so the node wave streams its
//    out-edges contiguously. Deletes phase2 launch, zbuf, evec.
//  - mbuf record slimmed 256B -> 128B: float2 (K0*m0_t, K1*m1_t) per lane
//    + one float4 u per slot (ubuf); node applies u with 3 fma/slot.

namespace {
constexpr int   NATOMS   = 100;
constexpr int   CAP      = 64;   // Poisson(16): P(deg>=64) ~ 1e-19
constexpr float PI_F     = 3.14159265358979323846f;
constexpr float INV4PI_F = 0.28209479177387814f;   // 1/sqrt(4*pi)
constexpr float SQRT3_F  = 1.7320508075688772f;
constexpr float CUT_F    = 6.0f;
constexpr float BASIS_C  = 2.3094010767585034f;    // sqrt(2/6)*sqrt(16)
constexpr float N0_F     = 0.17677669529663687f;   // 1/sqrt(32)
constexpr float K0_F = INV4PI_F * N0_F * 0.0625f;
constexpr float K1_F = SQRT3_F * INV4PI_F * N0_F * 0.0625f;
constexpr float P2SC = INV4PI_F * N0_F * (1.0f / 64.0f);
}

__device__ __forceinline__ float silu_fast(float x) {
  return x / (1.0f + __expf(-x));
}

__device__ __forceinline__ float block_reduce_sum(float v) {
  #pragma unroll
  for (int o = 32; o > 0; o >>= 1) v += __shfl_down(v, o, 64);
  __shared__ float ls[8];
  int lane = threadIdx.x & 63;
  int w    = threadIdx.x >> 6;
  if (lane == 0) ls[w] = v;
  __syncthreads();
  float s = 0.f;
  if (threadIdx.x == 0) {
    int nw = (blockDim.x + 63) >> 6;
    for (int i = 0; i < nw; ++i) s += ls[i];
  }
  return s;
}

// ---------------------------------------------------------------------------
// Tables: blocks [0,NATOMS) -> TI[a][j][2h+{0,1}] (float2-interleaved);
// block NATOMS -> G1T/G4T [comp][hidden] (transposed).
// ---------------------------------------------------------------------------
__global__ void table_kernel(const float* __restrict__ atom_emb,
                             const float* __restrict__ fc0_w2,
                             const float* __restrict__ fc1_w2,
                             const float* __restrict__ w_readout,
                             float* __restrict__ TI,
                             float* __restrict__ G1T, float* __restrict__ G4T) {
  int b = blockIdx.x;
  int tt = threadIdx.x;
  int j = tt >> 4;
  int h = tt & 15;
  if (b < NATOMS) {
    float s0 = 0.f, s1 = 0.f;
    #pragma unroll
    for (int d = 0; d < 32; ++d) {
      float x = atom_emb[b * 32 + d];
      s0 = fmaf(x, fc0_w2[j * 1024 + d * 16 + h], s0);
      s1 = fmaf(x, fc0_w2[j * 1024 + 512 + d * 16 + h], s1);
    }
    TI[b * 512 + j * 32 + 2 * h]     = s0;  // lane h: float2 at (j*16+h)
    TI[b * 512 + j * 32 + 2 * h + 1] = s1;
  } else {
    float g1 = 0.f, g4 = 0.f;
    #pragma unroll
    for (int k = 0; k < 16; ++k) {
      float r = w_readout[k];
      g1 = fmaf(fc1_w2[j * 1024 + h * 16 + k], r, g1);
      g4 = fmaf(fc1_w2[j * 1024 + 768 + h * 16 + k], r, g4);
    }
    G1T[h * 16 + j] = g1;    // [comp][hidden]: column t lane-consecutive
    G4T[h * 16 + j] = g4;
  }
}

// ---------------------------------------------------------------------------
// edge_kernel: one 16-lane group per edge, 2 edges/group.
//  - dst bucket: pos = atomicAdd(dcur[d]); mbuf[slot] float2/lane
//    (K0*m0_t, K1*m1_t) + ubuf[slot] = (ux,uy,uz,dist).
//  - src bucket: spos = atomicAdd(scur[s]); sbuf[s*CAP+spos] = u record
//    (for the fused phase-2 out-loop in node_kernel).
// ---------------------------------------------------------------------------
__global__ void __launch_bounds__(256)
edge_kernel(const int* __restrict__ ei,
            const float* __restrict__ coords,
            const int* __restrict__ an,
            const float* __restrict__ TI,
            const float* __restrict__ fc0_w1,
            int* __restrict__ dcur, int* __restrict__ scur,
            float2* __restrict__ mbuf,
            float4* __restrict__ ubuf,
            float4* __restrict__ sbuf,
            int E) {
  __shared__ float w1s[256];
  w1s[threadIdx.x] = fc0_w1[threadIdx.x];
  __syncthreads();
  int lane = threadIdx.x & 63;
  int g    = threadIdx.x >> 4;       // block group 0..15
  int t    = threadIdx.x & 15;
  int base = lane & 48;

  float w0c[16];
  #pragma unroll
  for (int k = 0; k < 16; ++k) w0c[k] = w1s[k * 16 + t];

  const float angc = PI_F / CUT_F;
  int e = blockIdx.x * 32 + g;
  #pragma unroll
  for (int rep = 0; rep < 2; ++rep, e += 16) {
    if (e < E) {
      int s = ei[e];
      int d = ei[E + e];
      float vx = coords[3 * s + 0] - coords[3 * d + 0];
      float vy = coords[3 * s + 1] - coords[3 * d + 1];
      float vz = coords[3 * s + 2] - coords[3 * d + 2];
      float dist = sqrtf(vx * vx + vy * vy + vz * vz);
      float inv  = 1.0f / fmaxf(dist, 1e-9f);
      float ux = vx * inv, uy = vy * inv, uz = vz * inv;
      float bc = (dist < CUT_F) ? (BASIS_C * inv) : 0.0f;

      int slotv = 0;
      if (t == 0) {
        float4 rec = make_float4(ux, uy, uz, dist);
        int pos  = atomicAdd(&dcur[d], 1);
        int spos = atomicAdd(&scur[s], 1);
        int dslot = d * CAP + min(pos, CAP - 1);
        ubuf[dslot] = rec;
        if (spos < CAP) sbuf[s * CAP + spos] = rec;
        slotv = dslot;
      }
      int slot = __shfl(slotv, base, 64);

      // h0_t via sine recurrence
      float ang = angc * dist;
      float sc = __sinf(ang);
      float tw = 2.0f * __cosf(ang);
      float sp = 0.f, acc = 0.f;
      #pragma unroll
      for (int k = 0; k < 16; ++k) {
        acc = fmaf(sc, w0c[k], acc);
        float sn = fmaf(tw, sc, -sp);
        sp = sc; sc = sn;
      }
      float h0t = silu_fast(acc * bc * 0.25f);

      int a = an[s];
      const float2* tp = (const float2*)(TI + a * 512) + t;
      float u0 = 0.f, u1 = 0.f;
      #pragma unroll
      for (int j = 0; j < 16; ++j) {
        float hj = __shfl(h0t, base + j, 64);
        float2 T = tp[j * 16];
        u0 = fmaf(hj, T.x, u0);
        u1 = fmaf(hj, T.y, u1);
      }
      mbuf[(size_t)slot * 16 + t] = make_float2(K0_F * u0, K1_F * u1);
    }
  }
}

// ---------------------------------------------------------------------------
// node_kernel (fused z-build + phase2 + readout): 256 thr = 4 waves = 4
// nodes/block; 4 groups x 16 lanes.
//  1) in-loop: stream dst-bucket slots (float2 + broadcast u), accumulate
//     z0/z1 components; butterfly across groups.
//  2) G-transform in registers -> lane (g,t) holds {Q,Px,Py,Pz}_t for g=0..3;
//     4 shfls give every lane Q_t,Px_t,Py_t,Pz_t.
//  3) out-loop: stream src-bucket u records; h1 recurrence; c += h1_t *
//     (Q_t + P_t . u). Block-reduce; one atomic (+ readout term).
// ---------------------------------------------------------------------------
__global__ void __launch_bounds__(256, 4)
node_kernel(const int* __restrict__ dcur,
            const int* __restrict__ scur,
            const float2* __restrict__ mbuf,
            const float4* __restrict__ ubuf,
            const float4* __restrict__ sbuf,
            const float* __restrict__ G1T,
            const float* __restrict__ G4T,
            const float* __restrict__ fc1_w1,
            const float* __restrict__ w_readout,
            float* __restrict__ out,
            int N) {
  __shared__ float ggs[512];          // [0:256)=G1T, [256:512)=G4T
  ggs[threadIdx.x]       = G1T[threadIdx.x];
  ggs[256 + threadIdx.x] = G4T[threadIdx.x];
  __syncthreads();

  int wave = threadIdx.x >> 6;
  int lane = threadIdx.x & 63;
  int g    = lane >> 4;
  int t    = lane & 15;
  int base = lane & 48;
  int node = blockIdx.x * 4 + wave;
  bool valid = node < N;

  float w1c[16];
  #pragma unroll
  for (int k = 0; k < 16; ++k) w1c[k] = fc1_w1[k * 16 + t];
  float rr = w_readout[t];

  int cin  = valid ? min(dcur[node], CAP) : 0;
  int cout = valid ? min(scur[node], CAP) : 0;
  size_t nb = (size_t)(valid ? node : 0) * CAP;

  // ---- 1) in-loop ----
  float a0 = 0.f, ax = 0.f, ay = 0.f, az = 0.f;
  for (int i = g; i < cin; i += 4) {
    float2 f  = mbuf[(nb + i) * 16 + t];
    float4 uu = ubuf[nb + i];            // group-uniform broadcast
    a0 += f.x;
    ax = fmaf(f.y, uu.x, ax);
    ay = fmaf(f.y, uu.y, ay);
    az = fmaf(f.y, uu.z, az);
  }
  a0 += __shfl_xor(a0, 16, 64); a0 += __shfl_xor(a0, 32, 64);
  ax += __shfl_xor(ax, 16, 64); ax += __shfl_xor(ax, 32, 64);
  ay += __shfl_xor(ay, 16, 64); ay += __shfl_xor(ay, 32, 64);
  az += __shfl_xor(az, 16, 64); az += __shfl_xor(az, 32, 64);

  // ---- 2) G-transform ----
  float srcv = (g == 0) ? a0 : ((g == 1) ? ax : (g == 2) ? ay : az);
  int tofs = (g == 0) ? 0 : 256;
  float o = 0.f;
  #pragma unroll
  for (int h = 0; h < 16; ++h) {
    float vh = __shfl(srcv, base + h, 64);
    o = fmaf(ggs[tofs + h * 16 + t], vh, o);
  }
  // distribute: every lane gets Q_t, Px_t, Py_t, Pz_t
  float Qt  = __shfl(o, t, 64);
  float Pxt = __shfl(o, 16 + t, 64);
  float Pyt = __shfl(o, 32 + t, 64);
  float Pzt = __shfl(o, 48 + t, 64);

  // ---- 3) out-loop (fused phase 2) ----
  const float angc = PI_F / CUT_F;
  float c = 0.f;
  for (int i = g; i < cout; i += 4) {
    float4 uu = sbuf[nb + i];            // group-uniform broadcast
    float dist = uu.w;
    float bc = (dist < CUT_F) ? (BASIS_C / fmaxf(dist, 1e-9f)) : 0.0f;
    float ang = angc * dist;
    float sc = __sinf(ang);
    float tw = 2.0f * __cosf(ang);
    float sp = 0.f, acc = 0.f;
    #pragma unroll
    for (int k = 0; k < 16; ++k) {
      acc = fmaf(sc, w1c[k], acc);
      float sn = fmaf(tw, sc, -sp);
      sp = sc; sc = sn;
    }
    float h1t = silu_fast(acc * bc * 0.25f);
    c = fmaf(h1t, fmaf(Pxt, uu.x, fmaf(Pyt, uu.y, fmaf(Pzt, uu.z, Qt))), c);
  }
  c *= P2SC;
  // readout term: 0.25 * z0_t * r_t (group 0 lanes hold z0 = a0)
  if (valid && g == 0) c = fmaf(a0 * rr, 0.25f, c);
  if (!valid) c = 0.f;

  float tot = block_reduce_sum(c);
  if (threadIdx.x == 0) atomicAdd(out, tot);
}

extern "C" void kernel_launch(void* const* d_in, const int* in_sizes, int n_in,
                              void* d_out, int out_size, void* d_ws, size_t ws_size,
                              hipStream_t stream) {
  const int*   an        = (const int*)d_in[0];
  const float* coords    = (const float*)d_in[1];
  const int*   ei        = (const int*)d_in[2];
  const float* atom_emb  = (const float*)d_in[3];
  const float* fc0_w1    = (const float*)d_in[4];
  const float* fc0_w2    = (const float*)d_in[5];
  const float* fc1_w1    = (const float*)d_in[6];
  const float* fc1_w2    = (const float*)d_in[7];
  const float* w_readout = (const float*)d_in[8];

  int N = in_sizes[0];
  int E = in_sizes[2] / 2;
  size_t slots = (size_t)N * CAP;

  // ws layout (16B-aligned float4 arrays first)
  float4* ubuf = (float4*)d_ws;                 // N*CAP  (10 MB)
  float4* sbuf = ubuf + slots;                  // N*CAP  (10 MB)
  float2* mbuf = (float2*)(sbuf + slots);       // N*CAP*16 (82 MB)
  float*  TI   = (float*)(mbuf + slots * 16);   // 100*512
  float*  G1T  = TI + NATOMS * 512;             // 256
  float*  G4T  = G1T + 256;                     // 256
  int*    dcur = (int*)(G4T + 256);             // N
  int*    scur = dcur + N;                      // N
  float*  out = (float*)d_out;

  hipMemsetAsync(dcur, 0, (size_t)2 * N * sizeof(int), stream);
  hipMemsetAsync(out, 0, sizeof(float), stream);

  int blk = 256;
  table_kernel<<<NATOMS + 1, blk, 0, stream>>>(
      atom_emb, fc0_w2, fc1_w2, w_readout, TI, G1T, G4T);

  edge_kernel<<<(E + 31) / 32, blk, 0, stream>>>(
      ei, coords, an, TI, fc0_w1, dcur, scur, mbuf, ubuf, sbuf, E);

  node_kernel<<<(N + 3) / 4, blk, 0, stream>>>(
      dcur, scur, mbuf, ubuf, sbuf, G1T, G4T, fc1_w1, w_readout, out, N);
}

// Round 13
// 150.946 us; speedup vs baseline: 1.2392x; 1.0022x over previous
//
#include <hip/hip_runtime.h>
#include <math.h>

// EquiTritonModel: N=10000 nodes, E=160000 edges, D=32, H=16, NB=16.
// R12 -> R13: node_kernel's fused out-loop carried a 16-deep serial sine
// recurrence per edge inside the per-node loop (~600 dependent cyc/wave,
// nothing to hide it). h1 depends only on dist -> hoisted to edge_kernel
// (edge-parallel; interleaves with the existing h0 recurrence for free ILP),
// stored bucketed-by-src in hbuf (64B/edge). node out-loop body is now
// ~8 instrs: coalesced h1 dword + broadcast u float4 + 4 fma.

namespace {
constexpr int   NATOMS   = 100;
constexpr int   CAP      = 64;   // Poisson(16): P(deg>=64) ~ 1e-19
constexpr float PI_F     = 3.14159265358979323846f;
constexpr float INV4PI_F = 0.28209479177387814f;   // 1/sqrt(4*pi)
constexpr float SQRT3_F  = 1.7320508075688772f;
constexpr float CUT_F    = 6.0f;
constexpr float BASIS_C  = 2.3094010767585034f;    // sqrt(2/6)*sqrt(16)
constexpr float N0_F     = 0.17677669529663687f;   // 1/sqrt(32)
constexpr float K0_F = INV4PI_F * N0_F * 0.0625f;
constexpr float K1_F = SQRT3_F * INV4PI_F * N0_F * 0.0625f;
constexpr float P2SC = INV4PI_F * N0_F * (1.0f / 64.0f);
}

__device__ __forceinline__ float silu_fast(float x) {
  return x / (1.0f + __expf(-x));
}

__device__ __forceinline__ float block_reduce_sum(float v) {
  #pragma unroll
  for (int o = 32; o > 0; o >>= 1) v += __shfl_down(v, o, 64);
  __shared__ float ls[8];
  int lane = threadIdx.x & 63;
  int w    = threadIdx.x >> 6;
  if (lane == 0) ls[w] = v;
  __syncthreads();
  float s = 0.f;
  if (threadIdx.x == 0) {
    int nw = (blockDim.x + 63) >> 6;
    for (int i = 0; i < nw; ++i) s += ls[i];
  }
  return s;
}

// ---------------------------------------------------------------------------
// Tables: blocks [0,NATOMS) -> TI[a][j][2h+{0,1}] (float2-interleaved);
// block NATOMS -> G1T/G4T [comp][hidden] (transposed).
// ---------------------------------------------------------------------------
__global__ void table_kernel(const float* __restrict__ atom_emb,
                             const float* __restrict__ fc0_w2,
                             const float* __restrict__ fc1_w2,
                             const float* __restrict__ w_readout,
                             float* __restrict__ TI,
                             float* __restrict__ G1T, float* __restrict__ G4T) {
  int b = blockIdx.x;
  int tt = threadIdx.x;
  int j = tt >> 4;
  int h = tt & 15;
  if (b < NATOMS) {
    float s0 = 0.f, s1 = 0.f;
    #pragma unroll
    for (int d = 0; d < 32; ++d) {
      float x = atom_emb[b * 32 + d];
      s0 = fmaf(x, fc0_w2[j * 1024 + d * 16 + h], s0);
      s1 = fmaf(x, fc0_w2[j * 1024 + 512 + d * 16 + h], s1);
    }
    TI[b * 512 + j * 32 + 2 * h]     = s0;  // lane h: float2 at (j*16+h)
    TI[b * 512 + j * 32 + 2 * h + 1] = s1;
  } else {
    float g1 = 0.f, g4 = 0.f;
    #pragma unroll
    for (int k = 0; k < 16; ++k) {
      float r = w_readout[k];
      g1 = fmaf(fc1_w2[j * 1024 + h * 16 + k], r, g1);
      g4 = fmaf(fc1_w2[j * 1024 + 768 + h * 16 + k], r, g4);
    }
    G1T[h * 16 + j] = g1;    // [comp][hidden]: column t lane-consecutive
    G4T[h * 16 + j] = g4;
  }
}

// ---------------------------------------------------------------------------
// edge_kernel: one 16-lane group per edge, 2 edges/group.
//  dst bucket: mbuf[dslot*16+t] = (K0*m0_t, K1*m1_t); ubuf[dslot] = u.
//  src bucket: sbuf[sslot] = u; hbuf[sslot*16+t] = h1_t (fc1 MLP hidden,
//  computed here via a second sine recurrence interleaved with h0's).
// ---------------------------------------------------------------------------
__global__ void __launch_bounds__(256)
edge_kernel(const int* __restrict__ ei,
            const float* __restrict__ coords,
            const int* __restrict__ an,
            const float* __restrict__ TI,
            const float* __restrict__ fc0_w1,
            const float* __restrict__ fc1_w1,
            int* __restrict__ dcur, int* __restrict__ scur,
            float2* __restrict__ mbuf,
            float4* __restrict__ ubuf,
            float4* __restrict__ sbuf,
            float* __restrict__ hbuf,
            int E) {
  int lane = threadIdx.x & 63;
  int g    = threadIdx.x >> 4;       // block group 0..15
  int t    = threadIdx.x & 15;
  int base = lane & 48;

  float w0c[16], w1c[16];
  #pragma unroll
  for (int k = 0; k < 16; ++k) {
    w0c[k] = fc0_w1[k * 16 + t];
    w1c[k] = fc1_w1[k * 16 + t];
  }

  const float angc = PI_F / CUT_F;
  int e = blockIdx.x * 32 + g;
  #pragma unroll
  for (int rep = 0; rep < 2; ++rep, e += 16) {
    if (e < E) {
      int s = ei[e];
      int d = ei[E + e];
      float vx = coords[3 * s + 0] - coords[3 * d + 0];
      float vy = coords[3 * s + 1] - coords[3 * d + 1];
      float vz = coords[3 * s + 2] - coords[3 * d + 2];
      float dist = sqrtf(vx * vx + vy * vy + vz * vz);
      float inv  = 1.0f / fmaxf(dist, 1e-9f);
      float ux = vx * inv, uy = vy * inv, uz = vz * inv;
      float bc = (dist < CUT_F) ? (BASIS_C * inv) : 0.0f;

      int dslotv = 0, sslotv = 0;
      if (t == 0) {
        float4 rec = make_float4(ux, uy, uz, dist);
        int pos  = atomicAdd(&dcur[d], 1);
        int spos = atomicAdd(&scur[s], 1);
        int dslot = d * CAP + min(pos, CAP - 1);
        int sslot = s * CAP + min(spos, CAP - 1);
        ubuf[dslot] = rec;
        sbuf[sslot] = rec;
        dslotv = dslot; sslotv = sslot;
      }
      int dslot = __shfl(dslotv, base, 64);
      int sslot = __shfl(sslotv, base, 64);

      // twin sine recurrences (h0 for fc0, h1 for fc1) — interleaved chains
      float ang = angc * dist;
      float sc0 = __sinf(ang);
      float tw  = 2.0f * __cosf(ang);
      float sc1 = sc0;
      float sp0 = 0.f, sp1 = 0.f, acc0 = 0.f, acc1 = 0.f;
      #pragma unroll
      for (int k = 0; k < 16; ++k) {
        acc0 = fmaf(sc0, w0c[k], acc0);
        acc1 = fmaf(sc1, w1c[k], acc1);
        float sn0 = fmaf(tw, sc0, -sp0); sp0 = sc0; sc0 = sn0;
        float sn1 = fmaf(tw, sc1, -sp1); sp1 = sc1; sc1 = sn1;
      }
      float h0t = silu_fast(acc0 * bc * 0.25f);
      float h1t = silu_fast(acc1 * bc * 0.25f);

      hbuf[(size_t)sslot * 16 + t] = h1t;

      int a = an[s];
      const float2* tp = (const float2*)(TI + a * 512) + t;
      float u0 = 0.f, u1 = 0.f;
      #pragma unroll
      for (int j = 0; j < 16; ++j) {
        float hj = __shfl(h0t, base + j, 64);
        float2 T = tp[j * 16];
        u0 = fmaf(hj, T.x, u0);
        u1 = fmaf(hj, T.y, u1);
      }
      mbuf[(size_t)dslot * 16 + t] = make_float2(K0_F * u0, K1_F * u1);
    }
  }
}

// ---------------------------------------------------------------------------
// node_kernel (fused z-build + phase2 + readout): 256 thr = 4 waves = 4
// nodes/block; 4 groups x 16 lanes. Both loops stream slim records now.
// ---------------------------------------------------------------------------
__global__ void __launch_bounds__(256, 4)
node_kernel(const int* __restrict__ dcur,
            const int* __restrict__ scur,
            const float2* __restrict__ mbuf,
            const float4* __restrict__ ubuf,
            const float4* __restrict__ sbuf,
            const float* __restrict__ hbuf,
            const float* __restrict__ G1T,
            const float* __restrict__ G4T,
            const float* __restrict__ w_readout,
            float* __restrict__ out,
            int N) {
  __shared__ float ggs[512];          // [0:256)=G1T, [256:512)=G4T
  ggs[threadIdx.x]       = G1T[threadIdx.x];
  ggs[256 + threadIdx.x] = G4T[threadIdx.x];
  __syncthreads();

  int wave = threadIdx.x >> 6;
  int lane = threadIdx.x & 63;
  int g    = lane >> 4;
  int t    = lane & 15;
  int base = lane & 48;
  int node = blockIdx.x * 4 + wave;
  bool valid = node < N;

  float rr = w_readout[t];
  int cin  = valid ? min(dcur[node], CAP) : 0;
  int cout = valid ? min(scur[node], CAP) : 0;
  size_t nb = (size_t)(valid ? node : 0) * CAP;

  // ---- 1) in-loop ----
  float a0 = 0.f, ax = 0.f, ay = 0.f, az = 0.f;
  for (int i = g; i < cin; i += 4) {
    float2 f  = mbuf[(nb + i) * 16 + t];
    float4 uu = ubuf[nb + i];            // group-uniform broadcast
    a0 += f.x;
    ax = fmaf(f.y, uu.x, ax);
    ay = fmaf(f.y, uu.y, ay);
    az = fmaf(f.y, uu.z, az);
  }
  a0 += __shfl_xor(a0, 16, 64); a0 += __shfl_xor(a0, 32, 64);
  ax += __shfl_xor(ax, 16, 64); ax += __shfl_xor(ax, 32, 64);
  ay += __shfl_xor(ay, 16, 64); ay += __shfl_xor(ay, 32, 64);
  az += __shfl_xor(az, 16, 64); az += __shfl_xor(az, 32, 64);

  // ---- 2) G-transform ----
  float srcv = (g == 0) ? a0 : ((g == 1) ? ax : (g == 2) ? ay : az);
  int tofs = (g == 0) ? 0 : 256;
  float o = 0.f;
  #pragma unroll
  for (int h = 0; h < 16; ++h) {
    float vh = __shfl(srcv, base + h, 64);
    o = fmaf(ggs[tofs + h * 16 + t], vh, o);
  }
  // distribute: every lane gets Q_t, Px_t, Py_t, Pz_t
  float Qt  = __shfl(o, t, 64);
  float Pxt = __shfl(o, 16 + t, 64);
  float Pyt = __shfl(o, 32 + t, 64);
  float Pzt = __shfl(o, 48 + t, 64);

  // ---- 3) out-loop (fused phase 2; h1 precomputed in edge_kernel) ----
  float c = 0.f;
  for (int i = g; i < cout; i += 4) {
    float h1 = hbuf[(nb + i) * 16 + t];  // coalesced 64B/group
    float4 uu = sbuf[nb + i];            // group-uniform broadcast
    c = fmaf(h1, fmaf(Pxt, uu.x, fmaf(Pyt, uu.y, fmaf(Pzt, uu.z, Qt))), c);
  }
  c *= P2SC;
  // readout term: 0.25 * z0_t * r_t (group 0 lanes hold z0 = a0)
  if (valid && g == 0) c = fmaf(a0 * rr, 0.25f, c);
  if (!valid) c = 0.f;

  float tot = block_reduce_sum(c);
  if (threadIdx.x == 0) atomicAdd(out, tot);
}

extern "C" void kernel_launch(void* const* d_in, const int* in_sizes, int n_in,
                              void* d_out, int out_size, void* d_ws, size_t ws_size,
                              hipStream_t stream) {
  const int*   an        = (const int*)d_in[0];
  const float* coords    = (const float*)d_in[1];
  const int*   ei        = (const int*)d_in[2];
  const float* atom_emb  = (const float*)d_in[3];
  const float* fc0_w1    = (const float*)d_in[4];
  const float* fc0_w2    = (const float*)d_in[5];
  const float* fc1_w1    = (const float*)d_in[6];
  const float* fc1_w2    = (const float*)d_in[7];
  const float* w_readout = (const float*)d_in[8];

  int N = in_sizes[0];
  int E = in_sizes[2] / 2;
  size_t slots = (size_t)N * CAP;

  // ws layout (16B-aligned arrays first). Total ~143 MB of ~256 MB ws.
  float4* ubuf = (float4*)d_ws;                 // N*CAP        (10 MB)
  float4* sbuf = ubuf + slots;                  // N*CAP        (10 MB)
  float2* mbuf = (float2*)(sbuf + slots);       // N*CAP*16     (82 MB)
  float*  hbuf = (float*)(mbuf + slots * 16);   // N*CAP*16     (41 MB)
  float*  TI   = hbuf + slots * 16;             // 100*512
  float*  G1T  = TI + NATOMS * 512;             // 256
  float*  G4T  = G1T + 256;                     // 256
  int*    dcur = (int*)(G4T + 256);             // N
  int*    scur = dcur + N;                      // N
  float*  out = (float*)d_out;

  hipMemsetAsync(dcur, 0, (size_t)2 * N * sizeof(int), stream);
  hipMemsetAsync(out, 0, sizeof(float), stream);

  int blk = 256;
  table_kernel<<<NATOMS + 1, blk, 0, stream>>>(
      atom_emb, fc0_w2, fc1_w2, w_readout, TI, G1T, G4T);

  edge_kernel<<<(E + 31) / 32, blk, 0, stream>>>(
      ei, coords, an, TI, fc0_w1, fc1_w1, dcur, scur,
      mbuf, ubuf, sbuf, hbuf, E);

  node_kernel<<<(N + 3) / 4, blk, 0, stream>>>(
      dcur, scur, mbuf, ubuf, sbuf, hbuf, G1T, G4T, w_readout, out, N);
}

// Round 14
// 149.077 us; speedup vs baseline: 1.2548x; 1.0125x over previous
//
#include <hip/hip_runtime.h>
#include <math.h>

// EquiTritonModel: N=10000 nodes, E=160000 edges, D=32, H=16, NB=16.
// R13 -> R14: edge_kernel (44us, VALUBusy 26%, ~13us VALU floor) was
// chain-serial: ei->coords->recurrence->TI->stores + 2 dependent slot
// atomics, twice sequentially. Restructured as a phased 2-edge pipeline:
// all input loads up front, slot atomics issued EARLY (latency overlaps
// the ~300cyc compute), both edges' recurrences/contractions interleaved,
// bucket stores last. Memsets + out-zero folded into table_kernel.

namespace {
constexpr int   NATOMS   = 100;
constexpr int   CAP      = 64;   // Poisson(16): P(deg>=64) ~ 1e-19
constexpr float PI_F     = 3.14159265358979323846f;
constexpr float INV4PI_F = 0.28209479177387814f;   // 1/sqrt(4*pi)
constexpr float SQRT3_F  = 1.7320508075688772f;
constexpr float CUT_F    = 6.0f;
constexpr float BASIS_C  = 2.3094010767585034f;    // sqrt(2/6)*sqrt(16)
constexpr float N0_F     = 0.17677669529663687f;   // 1/sqrt(32)
constexpr float K0_F = INV4PI_F * N0_F * 0.0625f;
constexpr float K1_F = SQRT3_F * INV4PI_F * N0_F * 0.0625f;
constexpr float P2SC = INV4PI_F * N0_F * (1.0f / 64.0f);
}

__device__ __forceinline__ float silu_fast(float x) {
  return x / (1.0f + __expf(-x));
}

__device__ __forceinline__ float block_reduce_sum(float v) {
  #pragma unroll
  for (int o = 32; o > 0; o >>= 1) v += __shfl_down(v, o, 64);
  __shared__ float ls[8];
  int lane = threadIdx.x & 63;
  int w    = threadIdx.x >> 6;
  if (lane == 0) ls[w] = v;
  __syncthreads();
  float s = 0.f;
  if (threadIdx.x == 0) {
    int nw = (blockDim.x + 63) >> 6;
    for (int i = 0; i < nw; ++i) s += ls[i];
  }
  return s;
}

// ---------------------------------------------------------------------------
// table_kernel: blocks [0,NATOMS) -> TI tables; block NATOMS -> G1T/G4T +
// out-zero; blocks > NATOMS zero dcur/scur (2N ints) — no hipMemset needed.
// ---------------------------------------------------------------------------
__global__ void table_kernel(const float* __restrict__ atom_emb,
                             const float* __restrict__ fc0_w2,
                             const float* __restrict__ fc1_w2,
                             const float* __restrict__ w_readout,
                             float* __restrict__ TI,
                             float* __restrict__ G1T, float* __restrict__ G4T,
                             int* __restrict__ dcur,   // dcur..dcur+2N zeroed
                             float* __restrict__ out,
                             int N2) {
  int b = blockIdx.x;
  int tt = threadIdx.x;
  if (b < NATOMS) {
    int j = tt >> 4;
    int h = tt & 15;
    float s0 = 0.f, s1 = 0.f;
    #pragma unroll
    for (int d = 0; d < 32; ++d) {
      float x = atom_emb[b * 32 + d];
      s0 = fmaf(x, fc0_w2[j * 1024 + d * 16 + h], s0);
      s1 = fmaf(x, fc0_w2[j * 1024 + 512 + d * 16 + h], s1);
    }
    TI[b * 512 + j * 32 + 2 * h]     = s0;
    TI[b * 512 + j * 32 + 2 * h + 1] = s1;
  } else if (b == NATOMS) {
    int j = tt >> 4;
    int h = tt & 15;
    float g1 = 0.f, g4 = 0.f;
    #pragma unroll
    for (int k = 0; k < 16; ++k) {
      float r = w_readout[k];
      g1 = fmaf(fc1_w2[j * 1024 + h * 16 + k], r, g1);
      g4 = fmaf(fc1_w2[j * 1024 + 768 + h * 16 + k], r, g4);
    }
    G1T[h * 16 + j] = g1;
    G4T[h * 16 + j] = g4;
    if (tt == 0) *out = 0.f;
  } else {
    int idx = (b - NATOMS - 1) * 256 + tt;
    if (idx < N2) dcur[idx] = 0;
  }
}

// ---------------------------------------------------------------------------
// edge_kernel: phased 2-edge pipeline. 16 groups x 16 lanes; group handles
// edges b*32+g and b*32+16+g. Phases: loads -> geometry+early atomics ->
// interleaved recurrences -> interleaved TI contraction -> stores.
// ---------------------------------------------------------------------------
__global__ void __launch_bounds__(256)
edge_kernel(const int* __restrict__ ei,
            const float* __restrict__ coords,
            const int* __restrict__ an,
            const float* __restrict__ TI,
            const float* __restrict__ fc0_w1,
            const float* __restrict__ fc1_w1,
            int* __restrict__ dcur, int* __restrict__ scur,
            float2* __restrict__ mbuf,
            float4* __restrict__ ubuf,
            float4* __restrict__ sbuf,
            float* __restrict__ hbuf,
            int E) {
  int lane = threadIdx.x & 63;
  int g    = threadIdx.x >> 4;       // block group 0..15
  int t    = threadIdx.x & 15;
  int base = lane & 48;

  float w0c[16], w1c[16];
  #pragma unroll
  for (int k = 0; k < 16; ++k) {
    w0c[k] = fc0_w1[k * 16 + t];
    w1c[k] = fc1_w1[k * 16 + t];
  }

  const float angc = PI_F / CUT_F;
  int eA = blockIdx.x * 32 + g;
  int eB = eA + 16;
  bool vA = eA < E, vB = eB < E;
  int eAc = vA ? eA : 0, eBc = vB ? eB : 0;

  // ---- phase 1: all input loads ----
  int sA = ei[eAc], dA = ei[E + eAc];
  int sB = ei[eBc], dB = ei[E + eBc];
  float sxA = coords[3 * sA + 0], syA = coords[3 * sA + 1], szA = coords[3 * sA + 2];
  float dxA = coords[3 * dA + 0], dyA = coords[3 * dA + 1], dzA = coords[3 * dA + 2];
  float sxB = coords[3 * sB + 0], syB = coords[3 * sB + 1], szB = coords[3 * sB + 2];
  float dxB = coords[3 * dB + 0], dyB = coords[3 * dB + 1], dzB = coords[3 * dB + 2];
  int aA = an[sA], aB = an[sB];

  // ---- phase 2: geometry + early slot atomics ----
  float vxA = sxA - dxA, vyA = syA - dyA, vzA = szA - dzA;
  float vxB = sxB - dxB, vyB = syB - dyB, vzB = szB - dzB;
  float distA = sqrtf(vxA * vxA + vyA * vyA + vzA * vzA);
  float distB = sqrtf(vxB * vxB + vyB * vyB + vzB * vzB);
  float ivA = 1.0f / fmaxf(distA, 1e-9f);
  float ivB = 1.0f / fmaxf(distB, 1e-9f);
  float uxA = vxA * ivA, uyA = vyA * ivA, uzA = vzA * ivA;
  float uxB = vxB * ivB, uyB = vyB * ivB, uzB = vzB * ivB;
  float bcA = (distA < CUT_F) ? (BASIS_C * ivA) : 0.0f;
  float bcB = (distB < CUT_F) ? (BASIS_C * ivB) : 0.0f;

  int dsAv = 0, ssAv = 0, dsBv = 0, ssBv = 0;
  if (t == 0) {
    if (vA) {
      int p = atomicAdd(&dcur[dA], 1), q = atomicAdd(&scur[sA], 1);
      dsAv = dA * CAP + min(p, CAP - 1);
      ssAv = sA * CAP + min(q, CAP - 1);
      ubuf[dsAv] = make_float4(uxA, uyA, uzA, distA);
      sbuf[ssAv] = make_float4(uxA, uyA, uzA, distA);
    }
    if (vB) {
      int p = atomicAdd(&dcur[dB], 1), q = atomicAdd(&scur[sB], 1);
      dsBv = dB * CAP + min(p, CAP - 1);
      ssBv = sB * CAP + min(q, CAP - 1);
      ubuf[dsBv] = make_float4(uxB, uyB, uzB, distB);
      sbuf[ssBv] = make_float4(uxB, uyB, uzB, distB);
    }
  }

  // ---- phase 3: interleaved sine recurrences (one chain per edge, two
  // accumulator pairs; sines shared between h0/h1) ----
  float angA = angc * distA, angB = angc * distB;
  float scA = __sinf(angA), twA = 2.0f * __cosf(angA), spA = 0.f;
  float scB = __sinf(angB), twB = 2.0f * __cosf(angB), spB = 0.f;
  float a0A = 0.f, a1A = 0.f, a0B = 0.f, a1B = 0.f;
  #pragma unroll
  for (int k = 0; k < 16; ++k) {
    a0A = fmaf(scA, w0c[k], a0A);
    a1A = fmaf(scA, w1c[k], a1A);
    a0B = fmaf(scB, w0c[k], a0B);
    a1B = fmaf(scB, w1c[k], a1B);
    float snA = fmaf(twA, scA, -spA); spA = scA; scA = snA;
    float snB = fmaf(twB, scB, -spB); spB = scB; scB = snB;
  }
  float h0A = silu_fast(a0A * bcA * 0.25f);
  float h1A = silu_fast(a1A * bcA * 0.25f);
  float h0B = silu_fast(a0B * bcB * 0.25f);
  float h1B = silu_fast(a1B * bcB * 0.25f);

  // slot broadcast (atomics issued long ago — latency covered)
  int dsA = __shfl(dsAv, base, 64);
  int ssA = __shfl(ssAv, base, 64);
  int dsB = __shfl(dsBv, base, 64);
  int ssB = __shfl(ssBv, base, 64);

  // ---- phase 4/5: interleaved TI loads + contraction ----
  const float2* tpA = (const float2*)(TI + aA * 512) + t;
  const float2* tpB = (const float2*)(TI + aB * 512) + t;
  float u0A = 0.f, u1A = 0.f, u0B = 0.f, u1B = 0.f;
  #pragma unroll
  for (int j = 0; j < 16; ++j) {
    float hjA = __shfl(h0A, base + j, 64);
    float hjB = __shfl(h0B, base + j, 64);
    float2 TA = tpA[j * 16];
    float2 TB = tpB[j * 16];
    u0A = fmaf(hjA, TA.x, u0A);
    u1A = fmaf(hjA, TA.y, u1A);
    u0B = fmaf(hjB, TB.x, u0B);
    u1B = fmaf(hjB, TB.y, u1B);
  }

  // ---- phase 6: bucket stores ----
  if (vA) {
    hbuf[(size_t)ssA * 16 + t] = h1A;
    mbuf[(size_t)dsA * 16 + t] = make_float2(K0_F * u0A, K1_F * u1A);
  }
  if (vB) {
    hbuf[(size_t)ssB * 16 + t] = h1B;
    mbuf[(size_t)dsB * 16 + t] = make_float2(K0_F * u0B, K1_F * u1B);
  }
}

// ---------------------------------------------------------------------------
// node_kernel (fused z-build + phase2 + readout): 256 thr = 4 waves = 4
// nodes/block; 4 groups x 16 lanes. Both loops stream slim records.
// ---------------------------------------------------------------------------
__global__ void __launch_bounds__(256, 4)
node_kernel(const int* __restrict__ dcur,
            const int* __restrict__ scur,
            const float2* __restrict__ mbuf,
            const float4* __restrict__ ubuf,
            const float4* __restrict__ sbuf,
            const float* __restrict__ hbuf,
            const float* __restrict__ G1T,
            const float* __restrict__ G4T,
            const float* __restrict__ w_readout,
            float* __restrict__ out,
            int N) {
  __shared__ float ggs[512];          // [0:256)=G1T, [256:512)=G4T
  ggs[threadIdx.x]       = G1T[threadIdx.x];
  ggs[256 + threadIdx.x] = G4T[threadIdx.x];
  __syncthreads();

  int wave = threadIdx.x >> 6;
  int lane = threadIdx.x & 63;
  int g    = lane >> 4;
  int t    = lane & 15;
  int base = lane & 48;
  int node = blockIdx.x * 4 + wave;
  bool valid = node < N;

  float rr = w_readout[t];
  int cin  = valid ? min(dcur[node], CAP) : 0;
  int cout = valid ? min(scur[node], CAP) : 0;
  size_t nb = (size_t)(valid ? node : 0) * CAP;

  // ---- 1) in-loop ----
  float a0 = 0.f, ax = 0.f, ay = 0.f, az = 0.f;
  for (int i = g; i < cin; i += 4) {
    float2 f  = mbuf[(nb + i) * 16 + t];
    float4 uu = ubuf[nb + i];            // group-uniform broadcast
    a0 += f.x;
    ax = fmaf(f.y, uu.x, ax);
    ay = fmaf(f.y, uu.y, ay);
    az = fmaf(f.y, uu.z, az);
  }
  a0 += __shfl_xor(a0, 16, 64); a0 += __shfl_xor(a0, 32, 64);
  ax += __shfl_xor(ax, 16, 64); ax += __shfl_xor(ax, 32, 64);
  ay += __shfl_xor(ay, 16, 64); ay += __shfl_xor(ay, 32, 64);
  az += __shfl_xor(az, 16, 64); az += __shfl_xor(az, 32, 64);

  // ---- 2) G-transform ----
  float srcv = (g == 0) ? a0 : ((g == 1) ? ax : (g == 2) ? ay : az);
  int tofs = (g == 0) ? 0 : 256;
  float o = 0.f;
  #pragma unroll
  for (int h = 0; h < 16; ++h) {
    float vh = __shfl(srcv, base + h, 64);
    o = fmaf(ggs[tofs + h * 16 + t], vh, o);
  }
  // distribute: every lane gets Q_t, Px_t, Py_t, Pz_t
  float Qt  = __shfl(o, t, 64);
  float Pxt = __shfl(o, 16 + t, 64);
  float Pyt = __shfl(o, 32 + t, 64);
  float Pzt = __shfl(o, 48 + t, 64);

  // ---- 3) out-loop (fused phase 2; h1 precomputed in edge_kernel) ----
  float c = 0.f;
  for (int i = g; i < cout; i += 4) {
    float h1 = hbuf[(nb + i) * 16 + t];  // coalesced 64B/group
    float4 uu = sbuf[nb + i];            // group-uniform broadcast
    c = fmaf(h1, fmaf(Pxt, uu.x, fmaf(Pyt, uu.y, fmaf(Pzt, uu.z, Qt))), c);
  }
  c *= P2SC;
  // readout term: 0.25 * z0_t * r_t (group 0 lanes hold z0 = a0)
  if (valid && g == 0) c = fmaf(a0 * rr, 0.25f, c);
  if (!valid) c = 0.f;

  float tot = block_reduce_sum(c);
  if (threadIdx.x == 0) atomicAdd(out, tot);
}

extern "C" void kernel_launch(void* const* d_in, const int* in_sizes, int n_in,
                              void* d_out, int out_size, void* d_ws, size_t ws_size,
                              hipStream_t stream) {
  const int*   an        = (const int*)d_in[0];
  const float* coords    = (const float*)d_in[1];
  const int*   ei        = (const int*)d_in[2];
  const float* atom_emb  = (const float*)d_in[3];
  const float* fc0_w1    = (const float*)d_in[4];
  const float* fc0_w2    = (const float*)d_in[5];
  const float* fc1_w1    = (const float*)d_in[6];
  const float* fc1_w2    = (const float*)d_in[7];
  const float* w_readout = (const float*)d_in[8];

  int N = in_sizes[0];
  int E = in_sizes[2] / 2;
  size_t slots = (size_t)N * CAP;

  // ws layout (16B-aligned arrays first). Total ~143 MB of ~256 MB ws.
  float4* ubuf = (float4*)d_ws;                 // N*CAP        (10 MB)
  float4* sbuf = ubuf + slots;                  // N*CAP        (10 MB)
  float2* mbuf = (float2*)(sbuf + slots);       // N*CAP*16     (82 MB)
  float*  hbuf = (float*)(mbuf + slots * 16);   // N*CAP*16     (41 MB)
  float*  TI   = hbuf + slots * 16;             // 100*512
  float*  G1T  = TI + NATOMS * 512;             // 256
  float*  G4T  = G1T + 256;                     // 256
  int*    dcur = (int*)(G4T + 256);             // N
  int*    scur = dcur + N;                      // N (contiguous after dcur)
  float*  out = (float*)d_out;

  int blk = 256;
  int zgrid = (2 * N + blk - 1) / blk;
  table_kernel<<<NATOMS + 1 + zgrid, blk, 0, stream>>>(
      atom_emb, fc0_w2, fc1_w2, w_readout, TI, G1T, G4T, dcur, out, 2 * N);

  edge_kernel<<<(E + 31) / 32, blk, 0, stream>>>(
      ei, coords, an, TI, fc0_w1, fc1_w1, dcur, scur,
      mbuf, ubuf, sbuf, hbuf, E);

  node_kernel<<<(N + 3) / 4, blk, 0, stream>>>(
      dcur, scur, mbuf, ubuf, sbuf, hbuf, G1T, G4T, w_readout, out, N);
}